// Round 4
// baseline (1666.362 us; speedup 1.0000x reference)
//
#include <hip/hip_runtime.h>

// Problem constants (fixed by the reference).
constexpr int Bn = 4;       // batch
constexpr int Tn = 2048;    // seq len
constexpr int Dn = 1024;    // hidden
constexpr int Rn = 64;      // max relative position
constexpr int RELP = 256;   // rel rows padded to 256
constexpr int QR_STRIDE = 132;

typedef __bf16 bf8 __attribute__((ext_vector_type(8)));
typedef float f32x4 __attribute__((ext_vector_type(4)));

__device__ __forceinline__ unsigned short f2bf(float f) {
    unsigned int u = __float_as_uint(f);
    u += 0x7fffu + ((u >> 16) & 1u);     // round-to-nearest-even
    return (unsigned short)(u >> 16);
}

#define GLDS(g, l)                                                            \
    __builtin_amdgcn_global_load_lds(                                         \
        (const __attribute__((address_space(1))) void*)(g),                   \
        (__attribute__((address_space(3))) void*)(l), 16, 0, 0)

#define MFMA_BF16(a, b, c) __builtin_amdgcn_mfma_f32_16x16x32_bf16(a, b, c, 0, 0, 0)

// ===========================================================================
// 256x256 GEMM, BK=32, 8 waves (2M x 4N), K=1024 -> 32 K-tiles.
// Ring-2 double buffer (T3 minimum-2-phase recipe, m230):
//   per K-tile: {STAGE next tile (4 GLDS) ; ds_read all frags ; setprio +
//   32 MFMA ; vmcnt(0) ; ONE s_barrier}. Loads issued BEFORE compute so HBM
//   latency hides under ds_read+MFMA; only one barrier per tile.
// LDS: A,B each 2 x [256][32] bf16 slots = 64 KB total -> 2 blocks/CU,
// 16 waves/CU (vs 96KB ring-3 = 1 block/CU last round).
// T2 swizzle (both-sides, verified 0 bank conflicts in round 3):
// K-tile stored as 128 physical rows of 128 B (8 x 16B chunks). Logical
// chunk c = row*4 + col8 lives at (prow=c>>3, pchunk=(c&7)^(prow&7)).
// GLDS writes LINEARLY (thread tid -> chunks tid, tid+512); the global
// SOURCE address is inverse-permuted; ds_read applies the same XOR.
// ===========================================================================
__device__ __forceinline__ void mfma_gemm_256_k32(
    const unsigned short* __restrict__ Ab,   // [256 rows][K=1024], tile base
    const unsigned short* __restrict__ Bb,   // [256 rows][K=1024], tile base
    f32x4 (&acc)[8][4], unsigned short* As, unsigned short* Bs)
{
    const int tid  = threadIdx.x;
    const int lane = tid & 63, wid = tid >> 6;
    const int wr = wid >> 2, wc = wid & 3;
    const int l15 = lane & 15, lq = lane >> 4;

    // swizzled per-lane ds_read offset (ushorts):
    // frag row r = base16 + l15, pc = ((l15&1)*4+lq) ^ ((l15>>1)&7)
    const int pc = (((l15 & 1) << 2) | lq) ^ ((l15 >> 1) & 7);
    const int lane_off = ((l15 >> 1) << 6) + (pc << 3);
    const int aoff = wr * 4096 + lane_off;   // + mi*512 (mi 0..7)
    const int boff = wc * 2048 + lane_off;   // + ni*512 (ni 0..3)

    // staging: thread tid fills physical chunks P0=tid, P1=tid+512;
    // inverse swizzle gives the global source element for each.
    const int P0 = tid, P1 = tid + 512;
    const int cr0 = P0 >> 3, cr1 = P1 >> 3;
    const int c0 = cr0 * 8 + ((P0 & 7) ^ (cr0 & 7));
    const int c1 = cr1 * 8 + ((P1 & 7) ^ (cr1 & 7));
    const size_t g0 = (size_t)(c0 >> 2) * Dn + (size_t)((c0 & 3) << 3);
    const size_t g1 = (size_t)(c1 >> 2) * Dn + (size_t)((c1 & 3) << 3);
    const int d0 = P0 * 8, d1 = P1 * 8;      // ushort offsets within slot

#define STAGE(src, buf)                                                       \
    do {                                                                      \
        GLDS((src) + g0, (buf) + d0);                                         \
        GLDS((src) + g1, (buf) + d1);                                         \
    } while (0)

    constexpr int NT = Dn / 32;              // 32 K-tiles

    // prologue: tile 0 -> slot 0
    STAGE(Ab, As);
    STAGE(Bb, Bs);
    asm volatile("s_waitcnt vmcnt(0)" ::: "memory");
    __builtin_amdgcn_s_barrier();

    bf8 a8[8], b4[4];
#pragma unroll 1
    for (int T = 0; T < NT; ++T) {
        const int cb = (T & 1) << 13;        // compute slot (8192 ushorts)
        const int sb = cb ^ 8192;            // stage slot
        // 1) issue next tile's 4 loads FIRST (max in-flight time)
        if (T + 1 < NT) {
            STAGE(Ab + (T + 1) * 32, As + sb);
            STAGE(Bb + (T + 1) * 32, Bs + sb);
        }
        // 2) ds_read all fragments of current tile (compiler inserts
        //    fine-grained lgkmcnt between reads and dependent MFMAs)
#pragma unroll
        for (int m = 0; m < 8; ++m)
            a8[m] = *(const bf8*)&As[cb + aoff + m * 512];
#pragma unroll
        for (int n = 0; n < 4; ++n)
            b4[n] = *(const bf8*)&Bs[cb + boff + n * 512];
        // 3) MFMA cluster (T5)
        __builtin_amdgcn_s_setprio(1);
#pragma unroll
        for (int m = 0; m < 8; ++m)
#pragma unroll
            for (int n = 0; n < 4; ++n)
                acc[m][n] = MFMA_BF16(a8[m], b4[n], acc[m][n]);
        __builtin_amdgcn_s_setprio(0);
        __builtin_amdgcn_sched_barrier(0);
        // 4) one vmcnt drain + ONE barrier per tile
        if (T + 1 < NT)
            asm volatile("s_waitcnt vmcnt(0)" ::: "memory");
        __builtin_amdgcn_s_barrier();
    }
#undef STAGE
}

// ---------------------------------------------------------------------------
// 128x128 legacy mainloop (kept for qr_gemm — tiny op, known-good)
// ---------------------------------------------------------------------------
__device__ __forceinline__ void mfma_gemm_128(
    const unsigned short* __restrict__ Ab,
    const unsigned short* __restrict__ Bb,
    int K, f32x4 acc[4][4],
    unsigned short* As, unsigned short* Bs)  // [2*128*32] each
{
    const int tid = threadIdx.x;
    const int r0  = tid >> 2;
    const int c8  = (tid & 3) * 8;
    const int lane = tid & 63;
    const int w    = tid >> 6;
    const int wm = (w & 1) * 64, wn = (w >> 1) * 64;
    const int l15 = lane & 15, lq = lane >> 4;

    const int nt = K >> 5;

    GLDS(Ab + (size_t)r0 * K + c8,        As + r0 * 32 + c8);
    GLDS(Ab + ((size_t)r0 + 64) * K + c8, As + (r0 + 64) * 32 + c8);
    GLDS(Bb + (size_t)r0 * K + c8,        Bs + r0 * 32 + c8);
    GLDS(Bb + ((size_t)r0 + 64) * K + c8, Bs + (r0 + 64) * 32 + c8);
    __syncthreads();

    int cur = 0;
    for (int t = 0; t < nt; ++t) {
        if (t + 1 < nt) {
            const int k0 = (t + 1) << 5;
            const int nb = (cur ^ 1) * (128 * 32);
            GLDS(Ab + (size_t)r0 * K + k0 + c8,        As + nb + r0 * 32 + c8);
            GLDS(Ab + ((size_t)r0 + 64) * K + k0 + c8, As + nb + (r0 + 64) * 32 + c8);
            GLDS(Bb + (size_t)r0 * K + k0 + c8,        Bs + nb + r0 * 32 + c8);
            GLDS(Bb + ((size_t)r0 + 64) * K + k0 + c8, Bs + nb + (r0 + 64) * 32 + c8);
        }
        const int cbuf = cur * (128 * 32);
        bf8 a[4], b[4];
#pragma unroll
        for (int i = 0; i < 4; ++i) {
            a[i] = *(const bf8*)&As[cbuf + (wm + i * 16 + l15) * 32 + lq * 8];
            b[i] = *(const bf8*)&Bs[cbuf + (wn + i * 16 + l15) * 32 + lq * 8];
        }
#pragma unroll
        for (int i = 0; i < 4; ++i)
#pragma unroll
            for (int j = 0; j < 4; ++j)
                acc[i][j] = MFMA_BF16(a[i], b[j], acc[i][j]);
        __syncthreads();
        cur ^= 1;
    }
}

// ---------------------------------------------------------------------------
// Prep kernels
// ---------------------------------------------------------------------------
__global__ __launch_bounds__(256) void cvt_bf16(
    const float* __restrict__ in, unsigned short* __restrict__ out, int n4)
{
    int i = blockIdx.x * 256 + threadIdx.x;
    if (i < n4) {
        float4 v = ((const float4*)in)[i];
        ushort4 o;
        o.x = f2bf(v.x); o.y = f2bf(v.y); o.z = f2bf(v.z); o.w = f2bf(v.w);
        ((ushort4*)out)[i] = o;
    }
}

__global__ __launch_bounds__(256) void wt_transpose(
    const float* __restrict__ w0, const float* __restrict__ w1,
    const float* __restrict__ w2, const float* __restrict__ w3,
    unsigned short* __restrict__ WT)
{
    __shared__ float t[32][33];
    const int z = blockIdx.z;
    const float* W = z == 0 ? w0 : z == 1 ? w1 : z == 2 ? w2 : w3;
    const int x = blockIdx.x * 32 + threadIdx.x;   // n
    const int y0 = blockIdx.y * 32;                // k
#pragma unroll
    for (int j = 0; j < 32; j += 8)
        t[threadIdx.y + j][threadIdx.x] = W[(size_t)(y0 + threadIdx.y + j) * Dn + x];
    __syncthreads();
    unsigned short* o = WT + (size_t)z * Dn * Dn;
    const int n0 = blockIdx.x * 32;
#pragma unroll
    for (int j = 0; j < 32; j += 8)
        o[(size_t)(n0 + threadIdx.y + j) * Dn + y0 + threadIdx.x] =
            f2bf(t[threadIdx.x][threadIdx.y + j]);
}

__global__ __launch_bounds__(256) void rel_pad(
    const float* __restrict__ st_rel, const float* __restrict__ ed_rel,
    unsigned short* __restrict__ relb)
{
    const int z = blockIdx.y;
    const float* in = z ? ed_rel : st_rel;
    const int i4 = blockIdx.x * 256 + threadIdx.x;
    const int row = (i4 * 4) >> 10;
    const int col = (i4 * 4) & 1023;
    ushort4 o; o.x = 0; o.y = 0; o.z = 0; o.w = 0;
    if (row < 2 * Rn + 1) {
        float4 v = *(const float4*)(in + (size_t)row * 1024 + col);
        o.x = f2bf(v.x); o.y = f2bf(v.y); o.z = f2bf(v.z); o.w = f2bf(v.w);
    }
    ((ushort4*)(relb + (size_t)z * RELP * 1024))[i4] = o;
}

// Bit-pack mask: 64 int32 -> 1 uint64 via ballot. 67 MB -> 2 MB.
__global__ __launch_bounds__(256) void mask_pack(
    const int* __restrict__ mask, unsigned long long* __restrict__ pm)
{
    const int g = blockIdx.x * 256 + threadIdx.x;
    const int v = mask[g];
    unsigned long long b = __ballot(v != 0);
    if ((threadIdx.x & 63) == 0) pm[g >> 6] = b;
}

// ---------------------------------------------------------------------------
// Projections (256², BK=32 ring-2): out[z] = bf16((X @ W[z]^T + b[z]) * scale)
// ---------------------------------------------------------------------------
__global__ __launch_bounds__(512, 4) void proj_gemm256(
    const unsigned short* __restrict__ Xb, const unsigned short* __restrict__ Wb,
    const float* __restrict__ b0, const float* __restrict__ b1,
    const float* __restrict__ b2, const float* __restrict__ b3,
    unsigned short* __restrict__ outQK, float qscale)
{
    __shared__ unsigned short As[2 * 8192], Bs[2 * 8192];   // 64 KB total
    const int z = blockIdx.z;
    const float* bias = z == 0 ? b0 : z == 1 ? b1 : z == 2 ? b2 : b3;
    const float scale = (z & 1) ? 1.0f : qscale;

    const unsigned short* Ab = Xb + (size_t)blockIdx.x * 256 * Dn;
    const unsigned short* Bb = Wb + ((size_t)z * Dn + blockIdx.y * 256) * Dn;

    f32x4 zero = {0.f, 0.f, 0.f, 0.f};
    f32x4 acc[8][4];
#pragma unroll
    for (int i = 0; i < 8; ++i)
#pragma unroll
        for (int j = 0; j < 4; ++j) acc[i][j] = zero;

    mfma_gemm_256_k32(Ab, Bb, acc, As, Bs);

    const int tid = threadIdx.x, lane = tid & 63, wid = tid >> 6;
    const int wr = wid >> 2, wc = wid & 3;
    const int l15 = lane & 15, lq = lane >> 4;
    unsigned short* out = outQK + (size_t)z * (size_t)Bn * Tn * Dn;
    const int row0 = blockIdx.x * 256 + wr * 128 + lq * 4;
    const int col0 = blockIdx.y * 256 + wc * 64 + l15;

#pragma unroll
    for (int ni = 0; ni < 4; ++ni) {
        const int col = col0 + ni * 16;
        const float bvv = bias[col];
#pragma unroll
        for (int mi = 0; mi < 8; ++mi)
#pragma unroll
            for (int r = 0; r < 4; ++r) {
                const int row = row0 + mi * 16 + r;
                out[(size_t)row * Dn + col] = f2bf((acc[mi][ni][r] + bvv) * scale);
            }
    }
}

// ---------------------------------------------------------------------------
// qr[z] = Q[z] @ rel[z]^T (legacy 128² path — tiny op)
// ---------------------------------------------------------------------------
__global__ __launch_bounds__(256) void qr_gemm(
    const unsigned short* __restrict__ QKb, const unsigned short* __restrict__ relb,
    float* __restrict__ QR)
{
    __shared__ unsigned short As[2 * 128 * 32], Bs[2 * 128 * 32];
    const int z = blockIdx.z;
    const unsigned short* Ab = QKb + ((size_t)(z * 2) * Bn * Tn + blockIdx.x * 128) * Dn;
    const unsigned short* Bb = relb + ((size_t)z * RELP + blockIdx.y * 128) * Dn;

    f32x4 zero = {0.f, 0.f, 0.f, 0.f};
    f32x4 acc[4][4];
#pragma unroll
    for (int i = 0; i < 4; ++i)
#pragma unroll
        for (int j = 0; j < 4; ++j) acc[i][j] = zero;

    mfma_gemm_128(Ab, Bb, Dn, acc, As, Bs);

    const int tid = threadIdx.x, lane = tid & 63, w = tid >> 6;
    const int wm = (w & 1) * 64, wn = (w >> 1) * 64;
    const int l15 = lane & 15, lq = lane >> 4;
    float* out = QR + (size_t)z * (size_t)Bn * Tn * QR_STRIDE;

#pragma unroll
    for (int ni = 0; ni < 4; ++ni) {
        const int col = blockIdx.y * 128 + wn + ni * 16 + l15;
        if (col >= 2 * Rn + 1) continue;
#pragma unroll
        for (int mi = 0; mi < 4; ++mi) {
#pragma unroll
            for (int r = 0; r < 4; ++r) {
                const int row = blockIdx.x * 128 + wm + mi * 16 + lq * 4 + r;
                out[(size_t)row * QR_STRIDE + col] = acc[mi][ni][r];
            }
        }
    }
}

// ---------------------------------------------------------------------------
// scores (256², BK=32 ring-2, bit-packed mask):
// Out[side,bt,i,j] = maskbit ? Q·K^T + qr[i,clip(j-i)] : -1e18
// ---------------------------------------------------------------------------
__global__ __launch_bounds__(512, 4) void scores_gemm256(
    const unsigned short* __restrict__ QKb, const float* __restrict__ QR,
    const unsigned int* __restrict__ pmask, float* __restrict__ Out)
{
    __shared__ unsigned short As[2 * 8192], Bs[2 * 8192];   // 64 KB total
    const int z = blockIdx.z;
    const int side = z >> 2, bt = z & 3;

    const unsigned short* Ab =
        QKb + ((size_t)side * 2 * Bn * Tn + (size_t)bt * Tn + blockIdx.x * 256) * Dn;
    const unsigned short* Bb =
        QKb + (((size_t)side * 2 + 1) * Bn * Tn + (size_t)bt * Tn + blockIdx.y * 256) * Dn;
    const float* QRb = QR + ((size_t)side * Bn * Tn + (size_t)bt * Tn) * QR_STRIDE;
    const unsigned int* pmb = pmask + (size_t)bt * Tn * (Tn / 32);
    float* outb = Out + ((size_t)side * Bn + bt) * (size_t)Tn * Tn;

    f32x4 zero = {0.f, 0.f, 0.f, 0.f};
    f32x4 acc[8][4];
#pragma unroll
    for (int i = 0; i < 8; ++i)
#pragma unroll
        for (int j = 0; j < 4; ++j) acc[i][j] = zero;

    mfma_gemm_256_k32(Ab, Bb, acc, As, Bs);

    const int tid = threadIdx.x, lane = tid & 63, wid = tid >> 6;
    const int wr = wid >> 2, wc = wid & 3;
    const int l15 = lane & 15, lq = lane >> 4;
    const int i0 = blockIdx.x * 256 + wr * 128 + lq * 4;
    const int j0 = blockIdx.y * 256 + wc * 64 + l15;

#pragma unroll
    for (int mi = 0; mi < 8; ++mi) {
#pragma unroll
        for (int r = 0; r < 4; ++r) {
            const int i = i0 + mi * 16 + r;
            const float* qrow = QRb + (size_t)i * QR_STRIDE;
            const unsigned int* mwrow = pmb + (size_t)i * (Tn / 32);
            float* orow = outb + (size_t)i * Tn;
#pragma unroll
            for (int ni = 0; ni < 4; ++ni) {
                const int j = j0 + ni * 16;
                int d = j - i;
                d = d < -Rn ? -Rn : (d > Rn ? Rn : d);
                const float qv = qrow[d + Rn];
                const unsigned int mw = mwrow[j >> 5];
                const bool ok = (mw >> (j & 31)) & 1u;
                orow[j] = ok ? acc[mi][ni][r] + qv : -1e18f;
            }
        }
    }
}

extern "C" void kernel_launch(void* const* d_in, const int* in_sizes, int n_in,
                              void* d_out, int out_size, void* d_ws, size_t ws_size,
                              hipStream_t stream) {
    const float* repre  = (const float*)d_in[0];
    const int*   mask   = (const int*)  d_in[1];
    const float* st_Wq  = (const float*)d_in[2];
    const float* st_bq  = (const float*)d_in[3];
    const float* st_Wk  = (const float*)d_in[4];
    const float* st_bk  = (const float*)d_in[5];
    const float* st_rel = (const float*)d_in[6];
    const float* ed_Wq  = (const float*)d_in[7];
    const float* ed_bq  = (const float*)d_in[8];
    const float* ed_Wk  = (const float*)d_in[9];
    const float* ed_bk  = (const float*)d_in[10];
    const float* ed_rel = (const float*)d_in[11];
    float* out = (float*)d_out;

    const size_t MT = (size_t)Bn * Tn;   // 8192

    unsigned short* Xb   = (unsigned short*)d_ws;          // [8192][1024]
    unsigned short* Wb   = Xb + MT * Dn;                   // [4][1024][1024]
    unsigned short* relb = Wb + (size_t)4 * Dn * Dn;       // [2][256][1024]
    unsigned short* QKb  = relb + (size_t)2 * RELP * Dn;   // [4][8192][1024]
    float* QRbuf = (float*)(QKb + (size_t)4 * MT * Dn);    // [2][8192][132]
    // pmask aliases Xb (dead after proj_gemm256; mask_pack runs after proj):
    unsigned long long* pmask = (unsigned long long*)Xb;   // [4][2048][32] = 2 MB

    const float qscale = 0.03125f;       // 1/sqrt(1024)
    dim3 blk(256);

    // Prep
    {
        int n4 = (int)(MT * Dn / 4);
        cvt_bf16<<<dim3((n4 + 255) / 256), blk, 0, stream>>>(repre, Xb, n4);
        wt_transpose<<<dim3(32, 32, 4), dim3(32, 8), 0, stream>>>(
            st_Wq, st_Wk, ed_Wq, ed_Wk, Wb);
        rel_pad<<<dim3(RELP * Dn / 4 / 256, 2), blk, 0, stream>>>(st_rel, ed_rel, relb);
    }

    // Projections (z: 0=st_q,1=st_k,2=ed_q,3=ed_k)
    proj_gemm256<<<dim3((int)MT / 256, Dn / 256, 4), dim3(512), 0, stream>>>(
        Xb, Wb, st_bq, st_bk, ed_bq, ed_bk, QKb, qscale);

    // Xb is dead now -> pack mask into its space (before scores)
    mask_pack<<<dim3((int)(Bn * (size_t)Tn * Tn / 256)), blk, 0, stream>>>(
        mask, pmask);

    // qr (z=side), legacy path
    qr_gemm<<<dim3((int)MT / 128, RELP / 128, 2), blk, 0, stream>>>(QKb, relb, QRbuf);

    // scores (z = side*4 + batch)
    scores_gemm256<<<dim3(Tn / 256, Tn / 256, 8), dim3(512), 0, stream>>>(
        QKb, QRbuf, (const unsigned int*)pmask, out);
}

// Round 5
// 535.926 us; speedup vs baseline: 3.1093x; 3.1093x over previous
//
#include <hip/hip_runtime.h>

// Problem constants (fixed by the reference).
constexpr int Bn = 4;       // batch
constexpr int Tn = 2048;    // seq len
constexpr int Dn = 1024;    // hidden
constexpr int Rn = 64;      // max relative position
constexpr int RELP = 256;   // rel rows padded to 256
constexpr int QR_STRIDE = 132;

typedef __bf16 bf8 __attribute__((ext_vector_type(8)));
typedef float f32x4 __attribute__((ext_vector_type(4)));

__device__ __forceinline__ unsigned short f2bf(float f) {
    unsigned int u = __float_as_uint(f);
    u += 0x7fffu + ((u >> 16) & 1u);     // round-to-nearest-even
    return (unsigned short)(u >> 16);
}

#define GLDS(g, l)                                                            \
    __builtin_amdgcn_global_load_lds(                                         \
        (const __attribute__((address_space(1))) void*)(g),                   \
        (__attribute__((address_space(3))) void*)(l), 16, 0, 0)

#define MFMA_BF16(a, b, c) __builtin_amdgcn_mfma_f32_16x16x32_bf16(a, b, c, 0, 0, 0)

// ===========================================================================
// 256x256 GEMM, BK=32, 8 waves (2M x 4N), K=1024 -> 32 K-tiles.
// Ring-2 double buffer (T3 minimum-2-phase recipe, m230):
//   per K-tile: {STAGE next tile (4 GLDS) ; ds_read all frags ; setprio +
//   32 MFMA ; vmcnt(0) ; ONE s_barrier}. Loads issued BEFORE compute so HBM
//   latency hides under ds_read+MFMA; only one barrier per tile.
// LDS: A,B each 2 x [256][32] bf16 slots = 64 KB total.
// T2 swizzle (both-sides, verified 0 bank conflicts in rounds 3-4):
// K-tile stored as 128 physical rows of 128 B (8 x 16B chunks). Logical
// chunk c = row*4 + col8 lives at (prow=c>>3, pchunk=(c&7)^(prow&7)).
// GLDS writes LINEARLY (thread tid -> chunks tid, tid+512); the global
// SOURCE address is inverse-permuted; ds_read applies the same XOR.
// NOTE (round-4 lesson): launch_bounds min-waves=4 forced VGPR=64 and
// spilled the accumulators -> 3.6 GB of scratch HBM traffic. Keep (512,2):
// mainloop needs ~96-128 VGPR live.
// ===========================================================================
__device__ __forceinline__ void mfma_gemm_256_k32(
    const unsigned short* __restrict__ Ab,   // [256 rows][K=1024], tile base
    const unsigned short* __restrict__ Bb,   // [256 rows][K=1024], tile base
    f32x4 (&acc)[8][4], unsigned short* As, unsigned short* Bs)
{
    const int tid  = threadIdx.x;
    const int lane = tid & 63, wid = tid >> 6;
    const int wr = wid >> 2, wc = wid & 3;
    const int l15 = lane & 15, lq = lane >> 4;

    // swizzled per-lane ds_read offset (ushorts):
    // frag row r = base16 + l15, pc = ((l15&1)*4+lq) ^ ((l15>>1)&7)
    const int pc = (((l15 & 1) << 2) | lq) ^ ((l15 >> 1) & 7);
    const int lane_off = ((l15 >> 1) << 6) + (pc << 3);
    const int aoff = wr * 4096 + lane_off;   // + mi*512 (mi 0..7)
    const int boff = wc * 2048 + lane_off;   // + ni*512 (ni 0..3)

    // staging: thread tid fills physical chunks P0=tid, P1=tid+512;
    // inverse swizzle gives the global source element for each.
    const int P0 = tid, P1 = tid + 512;
    const int cr0 = P0 >> 3, cr1 = P1 >> 3;
    const int c0 = cr0 * 8 + ((P0 & 7) ^ (cr0 & 7));
    const int c1 = cr1 * 8 + ((P1 & 7) ^ (cr1 & 7));
    const size_t g0 = (size_t)(c0 >> 2) * Dn + (size_t)((c0 & 3) << 3);
    const size_t g1 = (size_t)(c1 >> 2) * Dn + (size_t)((c1 & 3) << 3);
    const int d0 = P0 * 8, d1 = P1 * 8;      // ushort offsets within slot

#define STAGE(src, buf)                                                       \
    do {                                                                      \
        GLDS((src) + g0, (buf) + d0);                                         \
        GLDS((src) + g1, (buf) + d1);                                         \
    } while (0)

    constexpr int NT = Dn / 32;              // 32 K-tiles

    // prologue: tile 0 -> slot 0
    STAGE(Ab, As);
    STAGE(Bb, Bs);
    asm volatile("s_waitcnt vmcnt(0)" ::: "memory");
    __builtin_amdgcn_s_barrier();

    bf8 a8[8], b4[4];
#pragma unroll 1
    for (int T = 0; T < NT; ++T) {
        const int cb = (T & 1) << 13;        // compute slot (8192 ushorts)
        const int sb = cb ^ 8192;            // stage slot
        // 1) issue next tile's 4 loads FIRST (max in-flight time)
        if (T + 1 < NT) {
            STAGE(Ab + (T + 1) * 32, As + sb);
            STAGE(Bb + (T + 1) * 32, Bs + sb);
        }
        // 2) ds_read all fragments of current tile (compiler inserts
        //    fine-grained lgkmcnt between reads and dependent MFMAs)
#pragma unroll
        for (int m = 0; m < 8; ++m)
            a8[m] = *(const bf8*)&As[cb + aoff + m * 512];
#pragma unroll
        for (int n = 0; n < 4; ++n)
            b4[n] = *(const bf8*)&Bs[cb + boff + n * 512];
        // 3) MFMA cluster (T5)
        __builtin_amdgcn_s_setprio(1);
#pragma unroll
        for (int m = 0; m < 8; ++m)
#pragma unroll
            for (int n = 0; n < 4; ++n)
                acc[m][n] = MFMA_BF16(a8[m], b4[n], acc[m][n]);
        __builtin_amdgcn_s_setprio(0);
        __builtin_amdgcn_sched_barrier(0);
        // 4) one vmcnt drain + ONE barrier per tile
        if (T + 1 < NT)
            asm volatile("s_waitcnt vmcnt(0)" ::: "memory");
        __builtin_amdgcn_s_barrier();
    }
#undef STAGE
}

// ---------------------------------------------------------------------------
// 128x128 legacy mainloop (kept for qr_gemm — tiny op, known-good)
// ---------------------------------------------------------------------------
__device__ __forceinline__ void mfma_gemm_128(
    const unsigned short* __restrict__ Ab,
    const unsigned short* __restrict__ Bb,
    int K, f32x4 acc[4][4],
    unsigned short* As, unsigned short* Bs)  // [2*128*32] each
{
    const int tid = threadIdx.x;
    const int r0  = tid >> 2;
    const int c8  = (tid & 3) * 8;
    const int lane = tid & 63;
    const int w    = tid >> 6;
    const int wm = (w & 1) * 64, wn = (w >> 1) * 64;
    const int l15 = lane & 15, lq = lane >> 4;

    const int nt = K >> 5;

    GLDS(Ab + (size_t)r0 * K + c8,        As + r0 * 32 + c8);
    GLDS(Ab + ((size_t)r0 + 64) * K + c8, As + (r0 + 64) * 32 + c8);
    GLDS(Bb + (size_t)r0 * K + c8,        Bs + r0 * 32 + c8);
    GLDS(Bb + ((size_t)r0 + 64) * K + c8, Bs + (r0 + 64) * 32 + c8);
    __syncthreads();

    int cur = 0;
    for (int t = 0; t < nt; ++t) {
        if (t + 1 < nt) {
            const int k0 = (t + 1) << 5;
            const int nb = (cur ^ 1) * (128 * 32);
            GLDS(Ab + (size_t)r0 * K + k0 + c8,        As + nb + r0 * 32 + c8);
            GLDS(Ab + ((size_t)r0 + 64) * K + k0 + c8, As + nb + (r0 + 64) * 32 + c8);
            GLDS(Bb + (size_t)r0 * K + k0 + c8,        Bs + nb + r0 * 32 + c8);
            GLDS(Bb + ((size_t)r0 + 64) * K + k0 + c8, Bs + nb + (r0 + 64) * 32 + c8);
        }
        const int cbuf = cur * (128 * 32);
        bf8 a[4], b[4];
#pragma unroll
        for (int i = 0; i < 4; ++i) {
            a[i] = *(const bf8*)&As[cbuf + (wm + i * 16 + l15) * 32 + lq * 8];
            b[i] = *(const bf8*)&Bs[cbuf + (wn + i * 16 + l15) * 32 + lq * 8];
        }
#pragma unroll
        for (int i = 0; i < 4; ++i)
#pragma unroll
            for (int j = 0; j < 4; ++j)
                acc[i][j] = MFMA_BF16(a[i], b[j], acc[i][j]);
        __syncthreads();
        cur ^= 1;
    }
}

// ---------------------------------------------------------------------------
// Prep kernels
// ---------------------------------------------------------------------------
__global__ __launch_bounds__(256) void cvt_bf16(
    const float* __restrict__ in, unsigned short* __restrict__ out, int n4)
{
    int i = blockIdx.x * 256 + threadIdx.x;
    if (i < n4) {
        float4 v = ((const float4*)in)[i];
        ushort4 o;
        o.x = f2bf(v.x); o.y = f2bf(v.y); o.z = f2bf(v.z); o.w = f2bf(v.w);
        ((ushort4*)out)[i] = o;
    }
}

__global__ __launch_bounds__(256) void wt_transpose(
    const float* __restrict__ w0, const float* __restrict__ w1,
    const float* __restrict__ w2, const float* __restrict__ w3,
    unsigned short* __restrict__ WT)
{
    __shared__ float t[32][33];
    const int z = blockIdx.z;
    const float* W = z == 0 ? w0 : z == 1 ? w1 : z == 2 ? w2 : w3;
    const int x = blockIdx.x * 32 + threadIdx.x;   // n
    const int y0 = blockIdx.y * 32;                // k
#pragma unroll
    for (int j = 0; j < 32; j += 8)
        t[threadIdx.y + j][threadIdx.x] = W[(size_t)(y0 + threadIdx.y + j) * Dn + x];
    __syncthreads();
    unsigned short* o = WT + (size_t)z * Dn * Dn;
    const int n0 = blockIdx.x * 32;
#pragma unroll
    for (int j = 0; j < 32; j += 8)
        o[(size_t)(n0 + threadIdx.y + j) * Dn + y0 + threadIdx.x] =
            f2bf(t[threadIdx.x][threadIdx.y + j]);
}

__global__ __launch_bounds__(256) void rel_pad(
    const float* __restrict__ st_rel, const float* __restrict__ ed_rel,
    unsigned short* __restrict__ relb)
{
    const int z = blockIdx.y;
    const float* in = z ? ed_rel : st_rel;
    const int i4 = blockIdx.x * 256 + threadIdx.x;
    const int row = (i4 * 4) >> 10;
    const int col = (i4 * 4) & 1023;
    ushort4 o; o.x = 0; o.y = 0; o.z = 0; o.w = 0;
    if (row < 2 * Rn + 1) {
        float4 v = *(const float4*)(in + (size_t)row * 1024 + col);
        o.x = f2bf(v.x); o.y = f2bf(v.y); o.z = f2bf(v.z); o.w = f2bf(v.w);
    }
    ((ushort4*)(relb + (size_t)z * RELP * 1024))[i4] = o;
}

// Bit-pack mask: 64 int32 -> 1 uint64 via ballot. 67 MB -> 2 MB.
__global__ __launch_bounds__(256) void mask_pack(
    const int* __restrict__ mask, unsigned long long* __restrict__ pm)
{
    const int g = blockIdx.x * 256 + threadIdx.x;
    const int v = mask[g];
    unsigned long long b = __ballot(v != 0);
    if ((threadIdx.x & 63) == 0) pm[g >> 6] = b;
}

// ---------------------------------------------------------------------------
// Projections (256², BK=32 ring-2): out[z] = bf16((X @ W[z]^T + b[z]) * scale)
// ---------------------------------------------------------------------------
__global__ __launch_bounds__(512, 2) void proj_gemm256(
    const unsigned short* __restrict__ Xb, const unsigned short* __restrict__ Wb,
    const float* __restrict__ b0, const float* __restrict__ b1,
    const float* __restrict__ b2, const float* __restrict__ b3,
    unsigned short* __restrict__ outQK, float qscale)
{
    __shared__ unsigned short As[2 * 8192], Bs[2 * 8192];   // 64 KB total
    const int z = blockIdx.z;
    const float* bias = z == 0 ? b0 : z == 1 ? b1 : z == 2 ? b2 : b3;
    const float scale = (z & 1) ? 1.0f : qscale;

    const unsigned short* Ab = Xb + (size_t)blockIdx.x * 256 * Dn;
    const unsigned short* Bb = Wb + ((size_t)z * Dn + blockIdx.y * 256) * Dn;

    f32x4 zero = {0.f, 0.f, 0.f, 0.f};
    f32x4 acc[8][4];
#pragma unroll
    for (int i = 0; i < 8; ++i)
#pragma unroll
        for (int j = 0; j < 4; ++j) acc[i][j] = zero;

    mfma_gemm_256_k32(Ab, Bb, acc, As, Bs);

    const int tid = threadIdx.x, lane = tid & 63, wid = tid >> 6;
    const int wr = wid >> 2, wc = wid & 3;
    const int l15 = lane & 15, lq = lane >> 4;
    unsigned short* out = outQK + (size_t)z * (size_t)Bn * Tn * Dn;
    const int row0 = blockIdx.x * 256 + wr * 128 + lq * 4;
    const int col0 = blockIdx.y * 256 + wc * 64 + l15;

#pragma unroll
    for (int ni = 0; ni < 4; ++ni) {
        const int col = col0 + ni * 16;
        const float bvv = bias[col];
#pragma unroll
        for (int mi = 0; mi < 8; ++mi)
#pragma unroll
            for (int r = 0; r < 4; ++r) {
                const int row = row0 + mi * 16 + r;
                out[(size_t)row * Dn + col] = f2bf((acc[mi][ni][r] + bvv) * scale);
            }
    }
}

// ---------------------------------------------------------------------------
// qr[z] = Q[z] @ rel[z]^T (legacy 128² path — tiny op)
// ---------------------------------------------------------------------------
__global__ __launch_bounds__(256) void qr_gemm(
    const unsigned short* __restrict__ QKb, const unsigned short* __restrict__ relb,
    float* __restrict__ QR)
{
    __shared__ unsigned short As[2 * 128 * 32], Bs[2 * 128 * 32];
    const int z = blockIdx.z;
    const unsigned short* Ab = QKb + ((size_t)(z * 2) * Bn * Tn + blockIdx.x * 128) * Dn;
    const unsigned short* Bb = relb + ((size_t)z * RELP + blockIdx.y * 128) * Dn;

    f32x4 zero = {0.f, 0.f, 0.f, 0.f};
    f32x4 acc[4][4];
#pragma unroll
    for (int i = 0; i < 4; ++i)
#pragma unroll
        for (int j = 0; j < 4; ++j) acc[i][j] = zero;

    mfma_gemm_128(Ab, Bb, Dn, acc, As, Bs);

    const int tid = threadIdx.x, lane = tid & 63, w = tid >> 6;
    const int wm = (w & 1) * 64, wn = (w >> 1) * 64;
    const int l15 = lane & 15, lq = lane >> 4;
    float* out = QR + (size_t)z * (size_t)Bn * Tn * QR_STRIDE;

#pragma unroll
    for (int ni = 0; ni < 4; ++ni) {
        const int col = blockIdx.y * 128 + wn + ni * 16 + l15;
        if (col >= 2 * Rn + 1) continue;
#pragma unroll
        for (int mi = 0; mi < 4; ++mi) {
#pragma unroll
            for (int r = 0; r < 4; ++r) {
                const int row = blockIdx.x * 128 + wm + mi * 16 + lq * 4 + r;
                out[(size_t)row * QR_STRIDE + col] = acc[mi][ni][r];
            }
        }
    }
}

// ---------------------------------------------------------------------------
// scores (256², BK=32 ring-2, bit-packed mask):
// Out[side,bt,i,j] = maskbit ? Q·K^T + qr[i,clip(j-i)] : -1e18
// ---------------------------------------------------------------------------
__global__ __launch_bounds__(512, 2) void scores_gemm256(
    const unsigned short* __restrict__ QKb, const float* __restrict__ QR,
    const unsigned int* __restrict__ pmask, float* __restrict__ Out)
{
    __shared__ unsigned short As[2 * 8192], Bs[2 * 8192];   // 64 KB total
    const int z = blockIdx.z;
    const int side = z >> 2, bt = z & 3;

    const unsigned short* Ab =
        QKb + ((size_t)side * 2 * Bn * Tn + (size_t)bt * Tn + blockIdx.x * 256) * Dn;
    const unsigned short* Bb =
        QKb + (((size_t)side * 2 + 1) * Bn * Tn + (size_t)bt * Tn + blockIdx.y * 256) * Dn;
    const float* QRb = QR + ((size_t)side * Bn * Tn + (size_t)bt * Tn) * QR_STRIDE;
    const unsigned int* pmb = pmask + (size_t)bt * Tn * (Tn / 32);
    float* outb = Out + ((size_t)side * Bn + bt) * (size_t)Tn * Tn;

    f32x4 zero = {0.f, 0.f, 0.f, 0.f};
    f32x4 acc[8][4];
#pragma unroll
    for (int i = 0; i < 8; ++i)
#pragma unroll
        for (int j = 0; j < 4; ++j) acc[i][j] = zero;

    mfma_gemm_256_k32(Ab, Bb, acc, As, Bs);

    const int tid = threadIdx.x, lane = tid & 63, wid = tid >> 6;
    const int wr = wid >> 2, wc = wid & 3;
    const int l15 = lane & 15, lq = lane >> 4;
    const int i0 = blockIdx.x * 256 + wr * 128 + lq * 4;
    const int j0 = blockIdx.y * 256 + wc * 64 + l15;

#pragma unroll
    for (int mi = 0; mi < 8; ++mi) {
#pragma unroll
        for (int r = 0; r < 4; ++r) {
            const int i = i0 + mi * 16 + r;
            const float* qrow = QRb + (size_t)i * QR_STRIDE;
            const unsigned int* mwrow = pmb + (size_t)i * (Tn / 32);
            float* orow = outb + (size_t)i * Tn;
#pragma unroll
            for (int ni = 0; ni < 4; ++ni) {
                const int j = j0 + ni * 16;
                int d = j - i;
                d = d < -Rn ? -Rn : (d > Rn ? Rn : d);
                const float qv = qrow[d + Rn];
                const unsigned int mw = mwrow[j >> 5];
                const bool ok = (mw >> (j & 31)) & 1u;
                orow[j] = ok ? acc[mi][ni][r] + qv : -1e18f;
            }
        }
    }
}

extern "C" void kernel_launch(void* const* d_in, const int* in_sizes, int n_in,
                              void* d_out, int out_size, void* d_ws, size_t ws_size,
                              hipStream_t stream) {
    const float* repre  = (const float*)d_in[0];
    const int*   mask   = (const int*)  d_in[1];
    const float* st_Wq  = (const float*)d_in[2];
    const float* st_bq  = (const float*)d_in[3];
    const float* st_Wk  = (const float*)d_in[4];
    const float* st_bk  = (const float*)d_in[5];
    const float* st_rel = (const float*)d_in[6];
    const float* ed_Wq  = (const float*)d_in[7];
    const float* ed_bq  = (const float*)d_in[8];
    const float* ed_Wk  = (const float*)d_in[9];
    const float* ed_bk  = (const float*)d_in[10];
    const float* ed_rel = (const float*)d_in[11];
    float* out = (float*)d_out;

    const size_t MT = (size_t)Bn * Tn;   // 8192

    unsigned short* Xb   = (unsigned short*)d_ws;          // [8192][1024]
    unsigned short* Wb   = Xb + MT * Dn;                   // [4][1024][1024]
    unsigned short* relb = Wb + (size_t)4 * Dn * Dn;       // [2][256][1024]
    unsigned short* QKb  = relb + (size_t)2 * RELP * Dn;   // [4][8192][1024]
    float* QRbuf = (float*)(QKb + (size_t)4 * MT * Dn);    // [2][8192][132]
    // pmask aliases Xb (dead after proj_gemm256; mask_pack runs after proj):
    unsigned long long* pmask = (unsigned long long*)Xb;   // [4][2048][32] = 2 MB

    const float qscale = 0.03125f;       // 1/sqrt(1024)
    dim3 blk(256);

    // Prep
    {
        int n4 = (int)(MT * Dn / 4);
        cvt_bf16<<<dim3((n4 + 255) / 256), blk, 0, stream>>>(repre, Xb, n4);
        wt_transpose<<<dim3(32, 32, 4), dim3(32, 8), 0, stream>>>(
            st_Wq, st_Wk, ed_Wq, ed_Wk, Wb);
        rel_pad<<<dim3(RELP * Dn / 4 / 256, 2), blk, 0, stream>>>(st_rel, ed_rel, relb);
    }

    // Projections (z: 0=st_q,1=st_k,2=ed_q,3=ed_k)
    proj_gemm256<<<dim3((int)MT / 256, Dn / 256, 4), dim3(512), 0, stream>>>(
        Xb, Wb, st_bq, st_bk, ed_bq, ed_bk, QKb, qscale);

    // Xb is dead now -> pack mask into its space (before scores)
    mask_pack<<<dim3((int)(Bn * (size_t)Tn * Tn / 256)), blk, 0, stream>>>(
        mask, pmask);

    // qr (z=side), legacy path
    qr_gemm<<<dim3((int)MT / 128, RELP / 128, 2), blk, 0, stream>>>(QKb, relb, QRbuf);

    // scores (z = side*4 + batch)
    scores_gemm256<<<dim3(Tn / 256, Tn / 256, 8), dim3(512), 0, stream>>>(
        QKb, QRbuf, (const unsigned int*)pmask, out);
}

// Round 6
// 518.772 us; speedup vs baseline: 3.2121x; 1.0331x over previous
//
#include <hip/hip_runtime.h>

// Problem constants (fixed by the reference).
constexpr int Bn = 4;       // batch
constexpr int Tn = 2048;    // seq len
constexpr int Dn = 1024;    // hidden
constexpr int Rn = 64;      // max relative position
constexpr int RELP = 256;   // rel rows padded to 256
constexpr int QR_STRIDE = 132;

typedef __bf16 bf8 __attribute__((ext_vector_type(8)));
typedef float f32x4 __attribute__((ext_vector_type(4)));

__device__ __forceinline__ unsigned short f2bf(float f) {
    unsigned int u = __float_as_uint(f);
    u += 0x7fffu + ((u >> 16) & 1u);     // round-to-nearest-even
    return (unsigned short)(u >> 16);
}

#define GLDS(g, l)                                                            \
    __builtin_amdgcn_global_load_lds(                                         \
        (const __attribute__((address_space(1))) void*)(g),                   \
        (__attribute__((address_space(3))) void*)(l), 16, 0, 0)

#define MFMA_BF16(a, b, c) __builtin_amdgcn_mfma_f32_16x16x32_bf16(a, b, c, 0, 0, 0)

// Phase boundary: barrier, drain own ds_reads, pin ordering (rule #18).
#define PRE_MFMA()                                                            \
    do {                                                                      \
        __builtin_amdgcn_sched_barrier(0);                                    \
        __builtin_amdgcn_s_barrier();                                         \
        asm volatile("s_waitcnt lgkmcnt(0)" ::: "memory");                    \
        __builtin_amdgcn_sched_barrier(0);                                    \
    } while (0)
#define POST_MFMA()                                                           \
    do {                                                                      \
        __builtin_amdgcn_sched_barrier(0);                                    \
        __builtin_amdgcn_s_barrier();                                         \
    } while (0)

// ---------------------------------------------------------------------------
// Fragment read / MFMA helpers for the 8-phase mainloop.
// ---------------------------------------------------------------------------
__device__ __forceinline__ void rd_a4(bf8 (&a)[4][2], const unsigned short* As,
                                      int base, int mb, int ck0, int ck1) {
#pragma unroll
    for (int m = 0; m < 4; ++m) {
        a[m][0] = *(const bf8*)&As[base + (mb + m) * 1024 + ck0];
        a[m][1] = *(const bf8*)&As[base + (mb + m) * 1024 + ck1];
    }
}
__device__ __forceinline__ void rd_b2(bf8 (&b)[2][2], const unsigned short* Bs,
                                      int base, int nb, int ck0, int ck1) {
#pragma unroll
    for (int n = 0; n < 2; ++n) {
        b[n][0] = *(const bf8*)&Bs[base + (nb + n) * 1024 + ck0];
        b[n][1] = *(const bf8*)&Bs[base + (nb + n) * 1024 + ck1];
    }
}
__device__ __forceinline__ void mm8(f32x4 (&acc)[8][4], const bf8 (&a)[4][2],
                                    const bf8 (&b)[2][2], int mb, int nb) {
    __builtin_amdgcn_s_setprio(1);
#pragma unroll
    for (int m = 0; m < 4; ++m)
#pragma unroll
        for (int n = 0; n < 2; ++n) {
            f32x4 c = acc[mb + m][nb + n];
            c = MFMA_BF16(a[m][0], b[n][0], c);
            c = MFMA_BF16(a[m][1], b[n][1], c);
            acc[mb + m][nb + n] = c;
        }
    __builtin_amdgcn_s_setprio(0);
}

// ===========================================================================
// 256x256 GEMM, BK=64, 8 waves (2M x 4N), K=1024 -> 16 BK-tiles, 8-phase
// schedule (m201 template). LDS: per operand 2 buf x 2 half x [128][64] bf16
// = 64 KB; A+B = 128 KB -> 1 block/CU, 2 waves/SIMD (m201 operating point).
//
// Swizzle (proven 0-conflict in rounds 3/5): a half-tile is 128 phys rows of
// 128 B (8 x 16B chunks). Logical chunk (row rh, lc) at phys chunk
// lc ^ (rh&7). GLDS dest linear (wave-uniform base + lane*16 — m104 form);
// global SOURCE inverse-permuted; ds_read applies the same XOR.
//
// Per iter (tiles T=2j even->buf0, T+1->buf1), 8 phases; each phase:
//   {ds_read subtile ; stage 1 half-tile (2 GLDS) ; barrier ; lgkmcnt(0) ;
//    setprio(1) 16 MFMA setprio(0) ; barrier}.
// Quadrant order per tile: (a03,b01)(a03,b23)(a47,b23)(a47,b01) -> A freed
// after phase 2, B after phase 3 of its tile. Stage schedule (each stage >=1
// barrier after its slot's last read):
//   P0:A(T+1)h1  P1:B(T+1)h0  P2:B(T+1)h1  P3:A(T+2)h0
//   P4:A(T+2)h1  P5:B(T+2)h0  P6:B(T+2)h1  P7:A(T+3)h0
// Counted waits (T4): end-P3 vmcnt(2) (tile T+1 resident, P3's half in
// flight); end-P7 vmcnt(2) (tile T+2 resident, P7's half in flight).
// Never vmcnt(0) mid-loop; tail: vmcnt(0) at end-P3 of last iter.
// NOTE round-4 lesson: launch_bounds min-waves>2 forces VGPR<=128 and spills
// acc (3.6 GB scratch traffic). Keep (512,2): needs ~210 VGPR live.
// ===========================================================================
__device__ __forceinline__ void mfma_gemm_256_bk64(
    const unsigned short* __restrict__ Ab,   // [256 rows][K=1024] tile base
    const unsigned short* __restrict__ Bb,   // [256 rows][K=1024] tile base
    f32x4 (&acc)[8][4], unsigned short* As, unsigned short* Bs)
{
    const int tid  = threadIdx.x;
    const int lane = tid & 63, wid = tid >> 6;
    const int wr = wid >> 2, wc = wid & 3;
    const int l15 = lane & 15, lq = lane >> 4;
    const int ax  = l15 & 7;
    const int ck0 = (lq ^ ax) << 3;          // ushort off of chunk, ks=0
    const int ck1 = ((4 | lq) ^ ax) << 3;    // ks=1
    // A frag (mi,ks): row wr*128+mi*16+l15 -> half wr
    const int abase = wr * 8192 + l15 * 64;            // + mi*1024 + ck
    // B frag (ni,ks): row wc*64+ni*16+l15 -> half wc>>1
    const int bbase = (wc >> 1) * 8192 + (wc & 1) * 4096 + l15 * 64;

    // staging: thread tid fills phys chunks tid (rows 0-63) and tid+512
    // (rows 64-127) of a half-tile; source col inverse-swizzled.
    const int prow = tid >> 3;
    const int scol = ((tid & 7) ^ (prow & 7)) << 3;
    const int g0 = prow * Dn + scol;
    const int g1 = (prow + 64) * Dn + scol;  // (prow+64)&7 == prow&7
    const int d0 = tid * 8, d1 = tid * 8 + 4096;

#define STG_A(t, h, dstoff)                                                   \
    do {                                                                      \
        const unsigned short* s_ = Ab + (size_t)(h) * 128 * Dn + (t) * 64;    \
        GLDS(s_ + g0, As + (dstoff) + d0);                                    \
        GLDS(s_ + g1, As + (dstoff) + d1);                                    \
    } while (0)
#define STG_B(t, h, dstoff)                                                   \
    do {                                                                      \
        const unsigned short* s_ = Bb + (size_t)(h) * 128 * Dn + (t) * 64;    \
        GLDS(s_ + g0, Bs + (dstoff) + d0);                                    \
        GLDS(s_ + g1, Bs + (dstoff) + d1);                                    \
    } while (0)

    // prologue: tile0 fully + A(1)h0; wait tile0 (2 loads in flight)
    STG_A(0, 0, 0); STG_A(0, 1, 8192);
    STG_B(0, 0, 0); STG_B(0, 1, 8192);
    STG_A(1, 0, 16384);
    asm volatile("s_waitcnt vmcnt(2)" ::: "memory");
    __builtin_amdgcn_s_barrier();

    bf8 a[4][2], b[2][2];
#pragma unroll 1
    for (int j = 0; j < 8; ++j) {
        const bool st = j < 7;
        const int t0 = 2 * j;
        // ---- P0: rd a03+b01 (buf0); stage A(T+1)h1
        rd_a4(a, As, abase, 0, ck0, ck1);
        rd_b2(b, Bs, bbase, 0, ck0, ck1);
        STG_A(t0 + 1, 1, 16384 + 8192);
        PRE_MFMA(); mm8(acc, a, b, 0, 0); POST_MFMA();
        // ---- P1: rd b23 (buf0); stage B(T+1)h0
        rd_b2(b, Bs, bbase, 2, ck0, ck1);
        STG_B(t0 + 1, 0, 16384);
        PRE_MFMA(); mm8(acc, a, b, 0, 2); POST_MFMA();
        // ---- P2: rd a47 (buf0); stage B(T+1)h1
        rd_a4(a, As, abase, 4, ck0, ck1);
        STG_B(t0 + 1, 1, 16384 + 8192);
        PRE_MFMA(); mm8(acc, a, b, 4, 2); POST_MFMA();
        // ---- P3: rd b01 (buf0); stage A(T+2)h0; counted wait
        rd_b2(b, Bs, bbase, 0, ck0, ck1);
        if (st) STG_A(t0 + 2, 0, 0);
        PRE_MFMA(); mm8(acc, a, b, 4, 0);
        __builtin_amdgcn_sched_barrier(0);
        if (st) asm volatile("s_waitcnt vmcnt(2)" ::: "memory");
        else    asm volatile("s_waitcnt vmcnt(0)" ::: "memory");
        __builtin_amdgcn_s_barrier();
        // ---- P4: rd a03+b01 (buf1); stage A(T+2)h1
        rd_a4(a, As, 16384 + abase, 0, ck0, ck1);
        rd_b2(b, Bs, 16384 + bbase, 0, ck0, ck1);
        if (st) STG_A(t0 + 2, 1, 8192);
        PRE_MFMA(); mm8(acc, a, b, 0, 0); POST_MFMA();
        // ---- P5: rd b23 (buf1); stage B(T+2)h0
        rd_b2(b, Bs, 16384 + bbase, 2, ck0, ck1);
        if (st) STG_B(t0 + 2, 0, 0);
        PRE_MFMA(); mm8(acc, a, b, 0, 2); POST_MFMA();
        // ---- P6: rd a47 (buf1); stage B(T+2)h1
        rd_a4(a, As, 16384 + abase, 4, ck0, ck1);
        if (st) STG_B(t0 + 2, 1, 8192);
        PRE_MFMA(); mm8(acc, a, b, 4, 2); POST_MFMA();
        // ---- P7: rd b01 (buf1); stage A(T+3)h0; counted wait
        rd_b2(b, Bs, 16384 + bbase, 0, ck0, ck1);
        if (st) STG_A(t0 + 3, 0, 16384);
        PRE_MFMA(); mm8(acc, a, b, 4, 0);
        __builtin_amdgcn_sched_barrier(0);
        if (st) asm volatile("s_waitcnt vmcnt(2)" ::: "memory");
        __builtin_amdgcn_s_barrier();
    }
#undef STG_A
#undef STG_B
}

// ---------------------------------------------------------------------------
// 128x128 legacy mainloop (kept for qr_gemm — tiny op, known-good)
// ---------------------------------------------------------------------------
__device__ __forceinline__ void mfma_gemm_128(
    const unsigned short* __restrict__ Ab,
    const unsigned short* __restrict__ Bb,
    int K, f32x4 acc[4][4],
    unsigned short* As, unsigned short* Bs)  // [2*128*32] each
{
    const int tid = threadIdx.x;
    const int r0  = tid >> 2;
    const int c8  = (tid & 3) * 8;
    const int lane = tid & 63;
    const int w    = tid >> 6;
    const int wm = (w & 1) * 64, wn = (w >> 1) * 64;
    const int l15 = lane & 15, lq = lane >> 4;

    const int nt = K >> 5;

    GLDS(Ab + (size_t)r0 * K + c8,        As + r0 * 32 + c8);
    GLDS(Ab + ((size_t)r0 + 64) * K + c8, As + (r0 + 64) * 32 + c8);
    GLDS(Bb + (size_t)r0 * K + c8,        Bs + r0 * 32 + c8);
    GLDS(Bb + ((size_t)r0 + 64) * K + c8, Bs + (r0 + 64) * 32 + c8);
    __syncthreads();

    int cur = 0;
    for (int t = 0; t < nt; ++t) {
        if (t + 1 < nt) {
            const int k0 = (t + 1) << 5;
            const int nb = (cur ^ 1) * (128 * 32);
            GLDS(Ab + (size_t)r0 * K + k0 + c8,        As + nb + r0 * 32 + c8);
            GLDS(Ab + ((size_t)r0 + 64) * K + k0 + c8, As + nb + (r0 + 64) * 32 + c8);
            GLDS(Bb + (size_t)r0 * K + k0 + c8,        Bs + nb + r0 * 32 + c8);
            GLDS(Bb + ((size_t)r0 + 64) * K + k0 + c8, Bs + nb + (r0 + 64) * 32 + c8);
        }
        const int cbuf = cur * (128 * 32);
        bf8 a[4], b[4];
#pragma unroll
        for (int i = 0; i < 4; ++i) {
            a[i] = *(const bf8*)&As[cbuf + (wm + i * 16 + l15) * 32 + lq * 8];
            b[i] = *(const bf8*)&Bs[cbuf + (wn + i * 16 + l15) * 32 + lq * 8];
        }
#pragma unroll
        for (int i = 0; i < 4; ++i)
#pragma unroll
            for (int j = 0; j < 4; ++j)
                acc[i][j] = MFMA_BF16(a[i], b[j], acc[i][j]);
        __syncthreads();
        cur ^= 1;
    }
}

// ---------------------------------------------------------------------------
// Prep kernels
// ---------------------------------------------------------------------------
__global__ __launch_bounds__(256) void cvt_bf16(
    const float* __restrict__ in, unsigned short* __restrict__ out, int n4)
{
    int i = blockIdx.x * 256 + threadIdx.x;
    if (i < n4) {
        float4 v = ((const float4*)in)[i];
        ushort4 o;
        o.x = f2bf(v.x); o.y = f2bf(v.y); o.z = f2bf(v.z); o.w = f2bf(v.w);
        ((ushort4*)out)[i] = o;
    }
}

__global__ __launch_bounds__(256) void wt_transpose(
    const float* __restrict__ w0, const float* __restrict__ w1,
    const float* __restrict__ w2, const float* __restrict__ w3,
    unsigned short* __restrict__ WT)
{
    __shared__ float t[32][33];
    const int z = blockIdx.z;
    const float* W = z == 0 ? w0 : z == 1 ? w1 : z == 2 ? w2 : w3;
    const int x = blockIdx.x * 32 + threadIdx.x;   // n
    const int y0 = blockIdx.y * 32;                // k
#pragma unroll
    for (int j = 0; j < 32; j += 8)
        t[threadIdx.y + j][threadIdx.x] = W[(size_t)(y0 + threadIdx.y + j) * Dn + x];
    __syncthreads();
    unsigned short* o = WT + (size_t)z * Dn * Dn;
    const int n0 = blockIdx.x * 32;
#pragma unroll
    for (int j = 0; j < 32; j += 8)
        o[(size_t)(n0 + threadIdx.y + j) * Dn + y0 + threadIdx.x] =
            f2bf(t[threadIdx.x][threadIdx.y + j]);
}

__global__ __launch_bounds__(256) void rel_pad(
    const float* __restrict__ st_rel, const float* __restrict__ ed_rel,
    unsigned short* __restrict__ relb)
{
    const int z = blockIdx.y;
    const float* in = z ? ed_rel : st_rel;
    const int i4 = blockIdx.x * 256 + threadIdx.x;
    const int row = (i4 * 4) >> 10;
    const int col = (i4 * 4) & 1023;
    ushort4 o; o.x = 0; o.y = 0; o.z = 0; o.w = 0;
    if (row < 2 * Rn + 1) {
        float4 v = *(const float4*)(in + (size_t)row * 1024 + col);
        o.x = f2bf(v.x); o.y = f2bf(v.y); o.z = f2bf(v.z); o.w = f2bf(v.w);
    }
    ((ushort4*)(relb + (size_t)z * RELP * 1024))[i4] = o;
}

// Bit-pack mask: 64 int32 -> 1 uint64 via ballot. 67 MB -> 2 MB.
__global__ __launch_bounds__(256) void mask_pack(
    const int* __restrict__ mask, unsigned long long* __restrict__ pm)
{
    const int g = blockIdx.x * 256 + threadIdx.x;
    const int v = mask[g];
    unsigned long long b = __ballot(v != 0);
    if ((threadIdx.x & 63) == 0) pm[g >> 6] = b;
}

// ---------------------------------------------------------------------------
// Projections (256², BK=64 8-phase): out[z] = bf16((X @ W[z]^T + b[z])*scale)
// Flat grid 512; XCD-aware decode: each XCD owns 2 (y,z) W-panels.
// ---------------------------------------------------------------------------
__global__ __launch_bounds__(512, 2) void proj_gemm256(
    const unsigned short* __restrict__ Xb, const unsigned short* __restrict__ Wb,
    const float* __restrict__ b0, const float* __restrict__ b1,
    const float* __restrict__ b2, const float* __restrict__ b3,
    unsigned short* __restrict__ outQK, float qscale)
{
    __shared__ unsigned short As[2 * 16384], Bs[2 * 16384];   // 128 KB total
    const int bid = blockIdx.x;
    const int xcd = bid & 7, i = bid >> 3;
    const int p = xcd * 2 + (i >> 5);       // (y,z) panel index 0..15
    const int bx = i & 31;                  // M-tile
    const int by = p & 3;                   // N-tile
    const int z  = p >> 2;                  // weight select
    const float* bias = z == 0 ? b0 : z == 1 ? b1 : z == 2 ? b2 : b3;
    const float scale = (z & 1) ? 1.0f : qscale;

    const unsigned short* Ab = Xb + (size_t)bx * 256 * Dn;
    const unsigned short* Bb = Wb + ((size_t)z * Dn + by * 256) * Dn;

    f32x4 zero = {0.f, 0.f, 0.f, 0.f};
    f32x4 acc[8][4];
#pragma unroll
    for (int q = 0; q < 8; ++q)
#pragma unroll
        for (int r = 0; r < 4; ++r) acc[q][r] = zero;

    mfma_gemm_256_bk64(Ab, Bb, acc, As, Bs);

    const int tid = threadIdx.x, lane = tid & 63, wid = tid >> 6;
    const int wr = wid >> 2, wc = wid & 3;
    const int l15 = lane & 15, lq = lane >> 4;
    unsigned short* out = outQK + (size_t)z * (size_t)Bn * Tn * Dn;
    const int row0 = bx * 256 + wr * 128 + lq * 4;
    const int col0 = by * 256 + wc * 64 + l15;

#pragma unroll
    for (int ni = 0; ni < 4; ++ni) {
        const int col = col0 + ni * 16;
        const float bvv = bias[col];
#pragma unroll
        for (int mi = 0; mi < 8; ++mi)
#pragma unroll
            for (int r = 0; r < 4; ++r) {
                const int row = row0 + mi * 16 + r;
                out[(size_t)row * Dn + col] = f2bf((acc[mi][ni][r] + bvv) * scale);
            }
    }
}

// ---------------------------------------------------------------------------
// qr[z] = Q[z] @ rel[z]^T (legacy 128² path — tiny op)
// ---------------------------------------------------------------------------
__global__ __launch_bounds__(256) void qr_gemm(
    const unsigned short* __restrict__ QKb, const unsigned short* __restrict__ relb,
    float* __restrict__ QR)
{
    __shared__ unsigned short As[2 * 128 * 32], Bs[2 * 128 * 32];
    const int z = blockIdx.z;
    const unsigned short* Ab = QKb + ((size_t)(z * 2) * Bn * Tn + blockIdx.x * 128) * Dn;
    const unsigned short* Bb = relb + ((size_t)z * RELP + blockIdx.y * 128) * Dn;

    f32x4 zero = {0.f, 0.f, 0.f, 0.f};
    f32x4 acc[4][4];
#pragma unroll
    for (int i = 0; i < 4; ++i)
#pragma unroll
        for (int j = 0; j < 4; ++j) acc[i][j] = zero;

    mfma_gemm_128(Ab, Bb, Dn, acc, As, Bs);

    const int tid = threadIdx.x, lane = tid & 63, w = tid >> 6;
    const int wm = (w & 1) * 64, wn = (w >> 1) * 64;
    const int l15 = lane & 15, lq = lane >> 4;
    float* out = QR + (size_t)z * (size_t)Bn * Tn * QR_STRIDE;

#pragma unroll
    for (int ni = 0; ni < 4; ++ni) {
        const int col = blockIdx.y * 128 + wn + ni * 16 + l15;
        if (col >= 2 * Rn + 1) continue;
#pragma unroll
        for (int mi = 0; mi < 4; ++mi) {
#pragma unroll
            for (int r = 0; r < 4; ++r) {
                const int row = blockIdx.x * 128 + wm + mi * 16 + lq * 4 + r;
                out[(size_t)row * QR_STRIDE + col] = acc[mi][ni][r];
            }
        }
    }
}

// ---------------------------------------------------------------------------
// scores (256², BK=64 8-phase, bit-packed mask):
// Out[side,bt,i,j] = maskbit ? Q·K^T + qr[i,clip(j-i)] : -1e18
// Flat grid 512; XCD-aware decode: each XCD owns one (side,batch) slice
// (z = bid%8) -> Q/K panels L2-resident per XCD.
// ---------------------------------------------------------------------------
__global__ __launch_bounds__(512, 2) void scores_gemm256(
    const unsigned short* __restrict__ QKb, const float* __restrict__ QR,
    const unsigned int* __restrict__ pmask, float* __restrict__ Out)
{
    __shared__ unsigned short As[2 * 16384], Bs[2 * 16384];   // 128 KB total
    const int bid = blockIdx.x;
    const int z  = bid & 7;                 // slice -> XCD
    const int r8 = bid >> 3;
    const int bx = r8 & 7, by = r8 >> 3;
    const int side = z >> 2, bt = z & 3;

    const unsigned short* Ab =
        QKb + ((size_t)side * 2 * Bn * Tn + (size_t)bt * Tn + bx * 256) * Dn;
    const unsigned short* Bb =
        QKb + (((size_t)side * 2 + 1) * Bn * Tn + (size_t)bt * Tn + by * 256) * Dn;
    const float* QRb = QR + ((size_t)side * Bn * Tn + (size_t)bt * Tn) * QR_STRIDE;
    const unsigned int* pmb = pmask + (size_t)bt * Tn * (Tn / 32);
    float* outb = Out + ((size_t)side * Bn + bt) * (size_t)Tn * Tn;

    f32x4 zero = {0.f, 0.f, 0.f, 0.f};
    f32x4 acc[8][4];
#pragma unroll
    for (int q = 0; q < 8; ++q)
#pragma unroll
        for (int r = 0; r < 4; ++r) acc[q][r] = zero;

    mfma_gemm_256_bk64(Ab, Bb, acc, As, Bs);

    const int tid = threadIdx.x, lane = tid & 63, wid = tid >> 6;
    const int wr = wid >> 2, wc = wid & 3;
    const int l15 = lane & 15, lq = lane >> 4;
    const int i0 = bx * 256 + wr * 128 + lq * 4;
    const int j0 = by * 256 + wc * 64 + l15;

#pragma unroll
    for (int mi = 0; mi < 8; ++mi) {
#pragma unroll
        for (int r = 0; r < 4; ++r) {
            const int i = i0 + mi * 16 + r;
            const float* qrow = QRb + (size_t)i * QR_STRIDE;
            const unsigned int* mwrow = pmb + (size_t)i * (Tn / 32);
            float* orow = outb + (size_t)i * Tn;
#pragma unroll
            for (int ni = 0; ni < 4; ++ni) {
                const int j = j0 + ni * 16;
                int d = j - i;
                d = d < -Rn ? -Rn : (d > Rn ? Rn : d);
                const float qv = qrow[d + Rn];
                const unsigned int mw = mwrow[j >> 5];
                const bool ok = (mw >> (j & 31)) & 1u;
                orow[j] = ok ? acc[mi][ni][r] + qv : -1e18f;
            }
        }
    }
}

extern "C" void kernel_launch(void* const* d_in, const int* in_sizes, int n_in,
                              void* d_out, int out_size, void* d_ws, size_t ws_size,
                              hipStream_t stream) {
    const float* repre  = (const float*)d_in[0];
    const int*   mask   = (const int*)  d_in[1];
    const float* st_Wq  = (const float*)d_in[2];
    const float* st_bq  = (const float*)d_in[3];
    const float* st_Wk  = (const float*)d_in[4];
    const float* st_bk  = (const float*)d_in[5];
    const float* st_rel = (const float*)d_in[6];
    const float* ed_Wq  = (const float*)d_in[7];
    const float* ed_bq  = (const float*)d_in[8];
    const float* ed_Wk  = (const float*)d_in[9];
    const float* ed_bk  = (const float*)d_in[10];
    const float* ed_rel = (const float*)d_in[11];
    float* out = (float*)d_out;

    const size_t MT = (size_t)Bn * Tn;   // 8192

    unsigned short* Xb   = (unsigned short*)d_ws;          // [8192][1024]
    unsigned short* Wb   = Xb + MT * Dn;                   // [4][1024][1024]
    unsigned short* relb = Wb + (size_t)4 * Dn * Dn;       // [2][256][1024]
    unsigned short* QKb  = relb + (size_t)2 * RELP * Dn;   // [4][8192][1024]
    float* QRbuf = (float*)(QKb + (size_t)4 * MT * Dn);    // [2][8192][132]
    // pmask aliases Xb (dead after proj_gemm256; mask_pack runs after proj):
    unsigned long long* pmask = (unsigned long long*)Xb;   // [4][2048][32] = 2 MB

    const float qscale = 0.03125f;       // 1/sqrt(1024)
    dim3 blk(256);

    // Prep
    {
        int n4 = (int)(MT * Dn / 4);
        cvt_bf16<<<dim3((n4 + 255) / 256), blk, 0, stream>>>(repre, Xb, n4);
        wt_transpose<<<dim3(32, 32, 4), dim3(32, 8), 0, stream>>>(
            st_Wq, st_Wk, ed_Wq, ed_Wk, Wb);
        rel_pad<<<dim3(RELP * Dn / 4 / 256, 2), blk, 0, stream>>>(st_rel, ed_rel, relb);
    }

    // Projections (z: 0=st_q,1=st_k,2=ed_q,3=ed_k), flat 512 blocks
    proj_gemm256<<<dim3(512), dim3(512), 0, stream>>>(
        Xb, Wb, st_bq, st_bk, ed_bq, ed_bk, QKb, qscale);

    // Xb is dead now -> pack mask into its space (before scores)
    mask_pack<<<dim3((int)(Bn * (size_t)Tn * Tn / 256)), blk, 0, stream>>>(
        mask, pmask);

    // qr (z=side), legacy path
    qr_gemm<<<dim3((int)MT / 128, RELP / 128, 2), blk, 0, stream>>>(QKb, relb, QRbuf);

    // scores, flat 512 blocks (z = bid%8 -> XCD-pinned slice)
    scores_gemm256<<<dim3(512), dim3(512), 0, stream>>>(
        QKb, QRbuf, (const unsigned int*)pmask, out);
}